// Round 9
// baseline (109.392 us; speedup 1.0000x reference)
//
#include <hip/hip_runtime.h>

#define NEGC  (-1000000000.0f)
#define NEG2C (-1.4426950408889634e9f)
#define LOG2E 1.4426950408889634f
#define LN2   0.6931471805599453f

constexpr int B_=64, M_=16, L_=128;
constexpr long OFF_FTS=0;
constexpr long OFF_FMS=OFF_FTS+(long)B_*M_*L_;
constexpr long OFF_LA =OFF_FMS+(long)B_*M_*L_;
constexpr long OFF_ELA=OFF_LA+B_;
constexpr long OFF_LB =OFF_ELA+(long)B_*M_*L_;
constexpr long OFF_ELB=OFF_LB+(long)B_*L_;
constexpr long OFF_ENT=OFF_ELB+(long)B_*L_*M_*L_;
constexpr long OFF_EE =OFF_ENT+B_;

// bwd full tile: 16 rows x 128 cols, row stride 133 (bank 5m+l: 16 distinct),
// tile stride 2128 (mod32=16: cross-group needs 5*dm=16 mod 32 -> impossible)
// => per-step column writes are exactly 2-way (free, m136).
constexpr int RS=133;
constexpr int TS=2128;
constexpr int FR=17, FT=280, FG=560;   // fwd tiles (proven layout)

template<int CTRL>
__device__ __forceinline__ float dppf(float x){
  return __int_as_float(__builtin_amdgcn_update_dpp(0,__float_as_int(x),CTRL,0xF,0xF,true));
}
__device__ __forceinline__ float red16(float x){
  x += dppf<0xB1>(x); x += dppf<0x4E>(x); x += dppf<0x141>(x); x += dppf<0x140>(x);
  return x;
}
__device__ __forceinline__ float fexp2(float x){
#if __has_builtin(__builtin_amdgcn_exp2f)
  return __builtin_amdgcn_exp2f(x);
#else
  return __builtin_exp2f(x);
#endif
}
__device__ __forceinline__ float flog2(float x){
#if __has_builtin(__builtin_amdgcn_logf)
  return __builtin_amdgcn_logf(x);
#else
  return __builtin_log2f(x);
#endif
}
__device__ __forceinline__ float frcp(float x){
#if __has_builtin(__builtin_amdgcn_rcpf)
  return __builtin_amdgcn_rcpf(x);
#else
  return 1.0f/x;
#endif
}

// 64-thread blocks, 1 wave, no barriers.
// blk 0..15: fwd+entropy. blk 16..47: copies. blk 48..2095: backward (4 seqs).
__global__ __launch_bounds__(64, 4) void tok_main(
    const float* __restrict__ fwd_ts, const float* __restrict__ fwd_ms,
    const float* __restrict__ bwd_ts, const float* __restrict__ bwd_ms,
    const int* __restrict__ lengths, float* __restrict__ out)
{
  __shared__ float smem[4*TS];     // 34 KB: 4 full tiles (bwd) / fwd tiles fit inside
  const int tid  = threadIdx.x;
  const int blk  = blockIdx.x;
  const int m    = tid & 15;
  const int g    = tid >> 4;       // group 0..3

  if (blk >= 48) {
    // ================= backward: 4 consecutive j's, full-tile buffering =================
    const int bk  = blk - 48;      // 0..2047
    const int b   = bk >> 5;
    const int sub = bk & 31;
    const int j   = sub*4 + g;     // consecutive -> 32 KB contiguous flush region

    const int len   = lengths[b];
    const int lm1   = len - 1;
    const int thr   = 127 - j + m;            // em = (l >= thr)
    const int thrp  = (m==0) ? 0 : thr;       // w consumed iff (l>=thrp)&&(l<len)
    const float* tg = bwd_ts + (long)b*2048 + m*128;
    float* buf = smem + g*TS + m*RS;          // column write: bank 16g+5m+l, 2-way

    float W = 1.0f;      // linear scan state (renormalized)
    float G = 0.0f;      // ln(w) shift register (pre-update G = la(l-1-m))
    float refN = 0.0f;   // natural-log renorm accumulator
    float keepT = 1.0f, keepR = 0.0f;

    for (int c = 0; c < 4; ++c){
      const int lb = c << 5;
      const int thrC  = thr  - lb;
      const int thrpC = thrp - lb;
      const int lenC  = len  - lb;
      const int lm1C  = lm1  - lb;

      float T[32];
      {
        const float4* tp = (const float4*)(tg + lb);
        #pragma unroll
        for (int r=0; r<8; ++r){
          float4 v = tp[r];
          T[4*r]=v.x; T[4*r+1]=v.y; T[4*r+2]=v.z; T[4*r+3]=v.w;
        }
      }

      #pragma unroll
      for (int t=0; t<32; ++t){
        const bool em = (t >= thrC);
        const bool uw = (t >= thrpC) && (t < lenC);
        float e  = em ? fexp2(T[t]*LOG2E) : 1.0f;
        float x  = W * e;
        float s  = uw ? x : 0.0f;
        float tot = red16(s);
        float val = em ? (T[t] + (uw ? G : NEGC)) : NEGC;
        buf[lb + t] = val;
        keepT = (t == lm1C) ? tot : keepT;
        keepR = (t == lm1C) ? refN : keepR;
        float lg = flog2(tot)*LN2 + refN;     // feeds NEXT step's G only
        float Gs = dppf<0x111>(G);
        G = (m==0) ? lg : Gs;
        float Ws = dppf<0x111>(W);
        W = (m==0) ? tot : Ws;
        if (t==15 || t==31){                  // cheap renorm (no transcendental)
          int ef = (int)((__float_as_uint(tot) >> 23) & 255) - 127;
          W = ldexpf(W, -ef);
          refN += (float)ef * LN2;
        }
      }
    }
    if (m == 0)
      out[OFF_LB + (long)b*128 + j] = flog2(fmaxf(keepT, 1e-30f))*LN2 + keepR;

    // ---- flush: 32 KB fully sequential, 1 KB contiguous per instruction ----
    // same-wave LDS write->read ordering (lgkmcnt), no barrier needed
    #pragma unroll
    for (int tt=0; tt<4; ++tt){
      float* db = out + OFF_ELB + ((long)(b*128 + sub*4 + tt) << 11);
      const float* src = smem + tt*TS;
      #pragma unroll
      for (int inst=0; inst<8; ++inst){
        const int flat = inst*256 + tid*4;
        const int mm = flat >> 7, ll = flat & 127;
        const float* sp = src + mm*RS + ll;
        *(float4*)(db + flat) = make_float4(sp[0], sp[1], sp[2], sp[3]);
      }
    }

  } else if (blk < 16) {
    // ================= forward + entropy: 4 seqs (R8 structure, proven) =================
    const int b = blk*4 + g;
    const int len = lengths[b];
    const int lm1 = len - 1;
    const float* fts = fwd_ts + ((long)b*16 + m)*128;
    float w2=0.f, wh=0.f, stab=0.f, la_keep=0.f, h_keep=0.f;
    float* eT = smem + g*FG + m*FR;
    float* hT = smem + g*FG + FT + m*FR;
    const int fm2 = tid >> 2;
    const int fk2 = (tid & 3) << 2;

    for (int j0 = 0; j0 < 128; j0 += 4){
      float4 tv = *(const float4*)(fts + j0);
      float ta[4] = {tv.x, tv.y, tv.z, tv.w};
      #pragma unroll
      for (int kk=0; kk<4; ++kk){
        const int jj = j0 + kk;
        const bool valid = (m <= jj) && (jj < len);
        float c2 = ta[kk]*LOG2E + (valid ? w2 : NEG2C);
        float d  = c2 - stab;
        float s  = fexp2(d);
        float tot = red16(s);
        float lg = flog2(tot);
        float la = stab + lg;
        float q  = s * frcp(tot);
        float contrib = valid ? q * (wh + (lg - d)*LN2) : 0.f;
        float h = red16(contrib);
        eT[jj & 15] = c2*LN2;
        hT[jj & 15] = contrib;
        if (jj == lm1){ la_keep = la; h_keep = h; }
        float sW = dppf<0x111>(w2);
        float sH = dppf<0x111>(wh);
        w2 = (m==0) ? la : sW;
        wh = (m==0) ? h  : sH;
        stab = la;
      }
      if ((j0 & 15) == 12){
        const int jb = j0 - 12;
        #pragma unroll
        for (int g2=0; g2<4; ++g2){
          const int b2 = blk*4 + g2;
          const float* sb = smem + g2*FG;
          const float* sp = sb + fm2*FR + fk2;
          *(float4*)(out + OFF_ELA + ((long)b2*16 + fm2)*128 + jb + fk2) =
              make_float4(sp[0], sp[1], sp[2], sp[3]);
          const float* sp2 = sb + FT + fm2*FR + fk2;
          *(float4*)(out + OFF_EE + ((long)b2*16 + fm2)*128 + jb + fk2) =
              make_float4(sp2[0], sp2[1], sp2[2], sp2[3]);
        }
      }
    }
    if (m == 0){
      out[OFF_LA + b]  = la_keep * LN2;
      out[OFF_ENT + b] = h_keep;
    }

  } else {
    // ================= pass-through copies (blk 16..47) =================
    const int cbk = blk - 16;
    const float4* s0 = (const float4*)fwd_ts;
    const float4* s1 = (const float4*)fwd_ms;
    float4* d = (float4*)out;
    #pragma unroll
    for (int it=0; it<8; ++it){
      int idx = it*2048 + cbk*64 + tid;   // 0..16383
      float4 v = (idx < 8192) ? s0[idx] : s1[idx - 8192];
      d[idx] = v;
    }
  }
}

extern "C" void kernel_launch(void* const* d_in, const int* in_sizes, int n_in,
                              void* d_out, int out_size, void* d_ws, size_t ws_size,
                              hipStream_t stream) {
  const float* fts = (const float*)d_in[0];
  const float* fms = (const float*)d_in[1];
  const float* bts = (const float*)d_in[2];
  const float* bms = (const float*)d_in[3];
  const int*   len = (const int*)d_in[4];
  float* out = (float*)d_out;
  hipLaunchKernelGGL(tok_main, dim3(2096), dim3(64), 0, stream,
                     fts, fms, bts, bms, len, out);
}

// Round 11
// 99.402 us; speedup vs baseline: 1.1005x; 1.1005x over previous
//
#include <hip/hip_runtime.h>

#define NEGC  (-1000000000.0f)
#define NEG2C (-1.4426950408889634e9f)
#define LOG2E 1.4426950408889634f
#define LN2   0.6931471805599453f

constexpr int B_=64, M_=16, L_=128;
constexpr long OFF_FTS=0;
constexpr long OFF_FMS=OFF_FTS+(long)B_*M_*L_;
constexpr long OFF_LA =OFF_FMS+(long)B_*M_*L_;
constexpr long OFF_ELA=OFF_LA+B_;
constexpr long OFF_LB =OFF_ELA+(long)B_*M_*L_;
constexpr long OFF_ELB=OFF_LB+(long)B_*L_;
constexpr long OFF_ENT=OFF_ELB+(long)B_*L_*M_*L_;
constexpr long OFF_EE =OFF_ENT+B_;

constexpr int RSTR=33;            // bwd tile row stride (16 rows x 32 cols)
constexpr int GSTR=536;           // per-seq bwd tile (16*33+8)
constexpr int FR=17, FT=280, FG=560;  // fwd tiles (proven layout)

template<int CTRL>
__device__ __forceinline__ float dppf(float x){
  return __int_as_float(__builtin_amdgcn_update_dpp(0,__float_as_int(x),CTRL,0xF,0xF,true));
}
__device__ __forceinline__ float red16(float x){
  x += dppf<0xB1>(x); x += dppf<0x4E>(x); x += dppf<0x141>(x); x += dppf<0x140>(x);
  return x;
}
__device__ __forceinline__ float fexp2(float x){
#if __has_builtin(__builtin_amdgcn_exp2f)
  return __builtin_amdgcn_exp2f(x);
#else
  return __builtin_exp2f(x);
#endif
}
__device__ __forceinline__ float flog2(float x){
#if __has_builtin(__builtin_amdgcn_logf)
  return __builtin_amdgcn_logf(x);
#else
  return __builtin_log2f(x);
#endif
}
__device__ __forceinline__ float frcp(float x){
#if __has_builtin(__builtin_amdgcn_rcpf)
  return __builtin_amdgcn_rcpf(x);
#else
  return 1.0f/x;
#endif
}

// 64-thread blocks, 1 wave each, NO barriers.
// blk 0..15: fwd+entropy. blk 16..47: copies. blk 48..2095: backward (4 seqs, LPT order).
__global__ __launch_bounds__(64, 4) void tok_main(
    const float* __restrict__ fwd_ts, const float* __restrict__ fwd_ms,
    const float* __restrict__ bwd_ts, const float* __restrict__ bwd_ms,
    const int* __restrict__ lengths, float* __restrict__ out)
{
  __shared__ float smem[2240];
  const int tid  = threadIdx.x;
  const int blk  = blockIdx.x;
  const int m    = tid & 15;
  const int g    = tid >> 4;       // group 0..3

  if (blk >= 48) {
    // ================= backward: 4 consecutive j's, trivial-region skip =================
    const int bk  = blk - 48;      // 0..2047
    const int b   = bk >> 5;
    const int sub = 31 - (bk & 31);   // LPT: longest j-range dispatched first
    const int j   = sub*4 + g;
    const int jmax= sub*4 + 3;
    const int c0  = (127 - jmax) >> 5;   // first chunk containing any em=true

    const int len   = lengths[b];
    const int lm1   = len - 1;
    const int thr   = 127 - j + m;            // em = (l >= thr)
    const int thrp  = (m==0) ? 0 : thr;       // w consumed iff (l>=thrp)&&(l<len)
    const float* tg = bwd_ts + (long)b*2048 + m*128;
    float* buf = smem + g*GSTR + m*RSTR;
    const int fm = tid >> 3;                  // flush row 0..7
    const int fk = (tid & 7) << 2;            // flush col*4

    float W = 1.0f;      // exact entry state anywhere in the trivial region
    float G = 0.0f;
    float refN = 0.0f;
    float keepT = 1.0f, keepR = 0.0f;
    const float4 negv = make_float4(NEGC, NEGC, NEGC, NEGC);

    // ---- chunks fully in the trivial region: direct NEG stores (elb==NEG exact;
    //      if lm1 lands here LB = 0 exact, covered by keepT/keepR init) ----
    for (int c = 0; c < c0; ++c){
      const int lb = c << 5;
      #pragma unroll
      for (int g2=0; g2<4; ++g2){
        float* db = out + OFF_ELB + ((long)(b*128 + sub*4 + g2) << 11) + lb;
        *(float4*)(db + fm*128 + fk) = negv;
        *(float4*)(db + (fm+8)*128 + fk) = negv;
      }
    }

    // ---- scanned chunks ----
    for (int c = c0; c < 4; ++c){
      const int lb = c << 5;
      const int thrC  = thr  - lb;
      const int thrpC = thrp - lb;
      const int lenC  = len  - lb;
      const int lm1C  = lm1  - lb;

      float T[32], E[32];
      {
        const float4* tp = (const float4*)(tg + lb);
        #pragma unroll
        for (int r=0; r<8; ++r){
          float4 v = tp[r];
          T[4*r]=v.x; T[4*r+1]=v.y; T[4*r+2]=v.z; T[4*r+3]=v.w;
        }
      }
      #pragma unroll
      for (int t=0; t<32; ++t) E[t] = fexp2(T[t]*LOG2E);   // off-chain, pipelined

      #pragma unroll
      for (int t=0; t<32; ++t){
        const bool em = (t >= thrC);
        const bool uw = (t >= thrpC) && (t < lenC);
        float e  = em ? E[t] : 1.0f;
        float x  = W * e;
        float s  = uw ? x : 0.0f;
        float tot = red16(s);
        float val = em ? (T[t] + (uw ? G : NEGC)) : NEGC;
        buf[t] = val;
        keepT = (t == lm1C) ? tot : keepT;
        keepR = (t == lm1C) ? refN : keepR;
        float lg = flog2(tot)*LN2 + refN;     // feeds NEXT step's G only
        float Gs = dppf<0x111>(G);
        G = (m==0) ? lg : Gs;
        float Ws = dppf<0x111>(W);
        W = (m==0) ? tot : Ws;
        if (t==15 || t==31){                  // cheap renorm (no transcendental)
          int ef = (int)((__float_as_uint(tot) >> 23) & 255) - 127;
          W = ldexpf(W, -ef);
          refN += (float)ef * LN2;
        }
      }

      // flush chunk: 128-B sectors, interleaved with compute (R8 proven pattern)
      #pragma unroll
      for (int g2=0; g2<4; ++g2){
        const int j2 = sub*4 + g2;
        float* db = out + OFF_ELB + ((long)(b*128 + j2) << 11) + lb;
        const float* s1p = smem + g2*GSTR + fm*RSTR + fk;
        *(float4*)(db + fm*128 + fk) = make_float4(s1p[0], s1p[1], s1p[2], s1p[3]);
        const float* s2p = smem + g2*GSTR + (fm+8)*RSTR + fk;
        *(float4*)(db + (fm+8)*128 + fk) = make_float4(s2p[0], s2p[1], s2p[2], s2p[3]);
      }
    }
    if (m == 0)
      out[OFF_LB + (long)b*128 + j] = flog2(fmaxf(keepT, 1e-30f))*LN2 + keepR;

  } else if (blk < 16) {
    // ================= forward + entropy: 4 seqs (proven) =================
    const int b = blk*4 + g;
    const int len = lengths[b];
    const int lm1 = len - 1;
    const float* fts = fwd_ts + ((long)b*16 + m)*128;
    float w2=0.f, wh=0.f, stab=0.f, la_keep=0.f, h_keep=0.f;
    float* eT = smem + g*FG + m*FR;
    float* hT = smem + g*FG + FT + m*FR;
    const int fm2 = tid >> 2;
    const int fk2 = (tid & 3) << 2;

    for (int j0 = 0; j0 < 128; j0 += 4){
      float4 tv = *(const float4*)(fts + j0);
      float ta[4] = {tv.x, tv.y, tv.z, tv.w};
      #pragma unroll
      for (int kk=0; kk<4; ++kk){
        const int jj = j0 + kk;
        const bool valid = (m <= jj) && (jj < len);
        float c2 = ta[kk]*LOG2E + (valid ? w2 : NEG2C);
        float d  = c2 - stab;
        float s  = fexp2(d);
        float tot = red16(s);
        float lg = flog2(tot);
        float la = stab + lg;
        float q  = s * frcp(tot);
        float contrib = valid ? q * (wh + (lg - d)*LN2) : 0.f;
        float h = red16(contrib);
        eT[jj & 15] = c2*LN2;
        hT[jj & 15] = contrib;
        if (jj == lm1){ la_keep = la; h_keep = h; }
        float sW = dppf<0x111>(w2);
        float sH = dppf<0x111>(wh);
        w2 = (m==0) ? la : sW;
        wh = (m==0) ? h  : sH;
        stab = la;
      }
      if ((j0 & 15) == 12){
        const int jb = j0 - 12;
        #pragma unroll
        for (int g2=0; g2<4; ++g2){
          const int b2 = blk*4 + g2;
          const float* sb = smem + g2*FG;
          const float* sp = sb + fm2*FR + fk2;
          *(float4*)(out + OFF_ELA + ((long)b2*16 + fm2)*128 + jb + fk2) =
              make_float4(sp[0], sp[1], sp[2], sp[3]);
          const float* sp2 = sb + FT + fm2*FR + fk2;
          *(float4*)(out + OFF_EE + ((long)b2*16 + fm2)*128 + jb + fk2) =
              make_float4(sp2[0], sp2[1], sp2[2], sp2[3]);
        }
      }
    }
    if (m == 0){
      out[OFF_LA + b]  = la_keep * LN2;
      out[OFF_ENT + b] = h_keep;
    }

  } else {
    // ================= pass-through copies (blk 16..47) =================
    const int cbk = blk - 16;
    const float4* s0 = (const float4*)fwd_ts;
    const float4* s1 = (const float4*)fwd_ms;
    float4* d = (float4*)out;
    #pragma unroll
    for (int it=0; it<8; ++it){
      int idx = it*2048 + cbk*64 + tid;   // 0..16383
      float4 v = (idx < 8192) ? s0[idx] : s1[idx - 8192];
      d[idx] = v;
    }
  }
}

extern "C" void kernel_launch(void* const* d_in, const int* in_sizes, int n_in,
                              void* d_out, int out_size, void* d_ws, size_t ws_size,
                              hipStream_t stream) {
  const float* fts = (const float*)d_in[0];
  const float* fms = (const float*)d_in[1];
  const float* bts = (const float*)d_in[2];
  const float* bms = (const float*)d_in[3];
  const int*   len = (const int*)d_in[4];
  float* out = (float*)d_out;
  hipLaunchKernelGGL(tok_main, dim3(2096), dim3(64), 0, stream,
                     fts, fms, bts, bms, len, out);
}